// Round 17
// baseline (263.959 us; speedup 1.0000x reference)
//
#include <hip/hip_runtime.h>
#include <hip/hip_fp16.h>

#define D     2048
#define BLK   256
#define EPSV  1e-5f

typedef _Float16 h2 __attribute__((ext_vector_type(2)));

__device__ __forceinline__ unsigned int pkh(float a, float b) {
    return __builtin_bit_cast(unsigned int, __builtin_amdgcn_cvt_pkrtz(a, b));
}
__device__ __forceinline__ h2 ash2(unsigned int u) {
    return __builtin_bit_cast(h2, u);
}

// DPP row_shr:N add (old=0)
template<int CTRL>
__device__ __forceinline__ float dppadd(float x) {
    int y = __builtin_amdgcn_update_dpp(0, __builtin_bit_cast(int, x), CTRL, 0xf, 0xf, false);
    return x + __builtin_bit_cast(float, y);
}
// full wave64 sum; result valid in lanes 15,31,47,63
__device__ __forceinline__ float wave_sum(float x) {
    x += __shfl_xor(x, 32, 64);
    x += __shfl_xor(x, 16, 64);
    x = dppadd<0x111>(x);
    x = dppadd<0x112>(x);
    x = dppadd<0x114>(x);
    x = dppadd<0x118>(x);
    return x;
}

__device__ __forceinline__ float rdlane(float v, int l) {
    return __builtin_bit_cast(float, __builtin_amdgcn_readlane(__builtin_bit_cast(int, v), l));
}

// fast tanh via v_exp
__device__ __forceinline__ float ftanh(float x) {
    float xc = fminf(fmaxf(x, -10.f), 10.f);
    float e  = __expf(2.f * xc);
    return 1.f - 2.f * __builtin_amdgcn_rcpf(e + 1.f);
}

// ---- weight prep: Wq[c][p] = packed f16 pair of column c at d={2p,2p+1}
// c: 0-3 Wb, 4-7 Wm, 8-23 Wr(i*4+j). Grid: 24 blocks x 256 threads.
__global__ __launch_bounds__(256) void wt_kernel(
    const float* __restrict__ Wb, const float* __restrict__ Wm,
    const float* __restrict__ Wr, unsigned int* __restrict__ Wq)
{
    const int c = blockIdx.x;
    const int t = threadIdx.x;
    const float* src;
    int stride;
    if (c < 4)       { src = Wb + c;       stride = 4;  }
    else if (c < 8)  { src = Wm + (c - 4); stride = 4;  }
    else             { src = Wr + (c - 8); stride = 16; }

    #pragma unroll
    for (int k = 0; k < 4; ++k) {
        int p = t + 256 * k;                    // pair index 0..1023
        float a = src[(2 * p)     * stride];
        float b = src[(2 * p + 1) * stride];
        Wq[c * 1024 + p] = pkh(a, b);
    }
}

__global__ __launch_bounds__(BLK, 7) void hc_kernel(
    const float* __restrict__ lo,      // [tok, D]
    const float* __restrict__ hs,      // [tok, 4, D]
    const float* __restrict__ Bm,      // [1,4]
    const float* __restrict__ Am,      // [4,1]
    const float* __restrict__ Ar,      // [4,4]
    const float* __restrict__ s_alpha, // [4,4]
    const float* __restrict__ s_beta,  // [1,4]
    const unsigned int* __restrict__ Wq, // [24][1024] packed f16 weight pairs
    float* __restrict__ out)           // [tok, 4, D]
{
    __shared__ __align__(16) unsigned int hq[4][1024];   // 16 KB packed f16 hidden rows
    __shared__ __align__(16) unsigned int hbar[1024];    //  4 KB packed f16 H_bar
    __shared__ float pred[24];
    __shared__ float sred[4][2];

    const int tid  = threadIdx.x;
    const int wave = tid >> 6;             // wave owns hidden row `wave`
    const int lane = tid & 63;
    const long tok = blockIdx.x;

    const float4* hs4  = (const float4*)(hs + tok * (long)(4 * D));
    const float4* lo4  = (const float4*)(lo + tok * (long)D);
    float4*       out4 = (float4*)(out + tok * (long)(4 * D));

    // ---- P1: wave streams its full row (unroll 4 caps in-flight regs), stats + f16 pack ----
    float s = 0.f, q = 0.f;
    uint2* hqw = (uint2*)hq[wave];
    #pragma unroll 4
    for (int k = 0; k < 8; ++k) {
        int i4 = 64 * k + lane;
        float4 v = hs4[wave * 512 + i4];
        s += v.x + v.y + v.z + v.w;
        q += v.x * v.x + v.y * v.y + v.z * v.z + v.w * v.w;
        hqw[i4] = make_uint2(pkh(v.x, v.y), pkh(v.z, v.w));
    }
    float4 lv0 = lo4[tid];                 // prefetch lo for P3
    float4 lv1 = lo4[tid + 256];
    s = wave_sum(s);
    q = wave_sum(q);
    if (lane == 15) { sred[wave][0] = s; sred[wave][1] = q; }
    __syncthreads();                       // bar1: hq + sred ready

    // ---- P1.5: build packed-f16 H_bar; thread owns uint2 slots {tid, tid+256} ----
    {
        float c1[4];                       // 0.25*rs[n]
        float c0 = 0.f;                    // -0.25*sum(mu*rs)
        #pragma unroll
        for (int n = 0; n < 4; ++n) {
            float ss = sred[n][0];
            float qq = sred[n][1];
            float m   = ss * (1.f / D);
            float var = qq * (1.f / D) - m * m;
            float r   = rsqrtf(var + EPSV);
            c1[n] = 0.25f * r;
            c0   -= 0.25f * r * m;
        }
        #pragma unroll
        for (int t2 = 0; t2 < 2; ++t2) {
            int slot = tid + 256 * t2;
            float b0 = c0, b1 = c0, b2 = c0, b3 = c0;
            #pragma unroll
            for (int n = 0; n < 4; ++n) {
                uint2 rw = ((const uint2*)hq[n])[slot];
                h2 a = ash2(rw.x), b = ash2(rw.y);
                b0 += (float)a[0] * c1[n];
                b1 += (float)a[1] * c1[n];
                b2 += (float)b[0] * c1[n];
                b3 += (float)b[1] * c1[n];
            }
            ((uint2*)hbar)[slot] = make_uint2(pkh(b0, b1), pkh(b2, b3));
        }
    }
    __syncthreads();                       // bar2: hbar ready

    // ---- P2: wave w dots cols 6w..6w+5 against full H_bar ----
    float acc[6] = {0.f, 0.f, 0.f, 0.f, 0.f, 0.f};
    const int c0i = wave * 6;
    const uint2* Wq2 = (const uint2*)Wq;   // [24][512]
    const uint2* hb2 = (const uint2*)hbar; // [512]

    #pragma unroll
    for (int k = 0; k < 8; ++k) {
        int i4 = 64 * k + lane;
        uint2 hb = hb2[i4];
        h2 plo = ash2(hb.x), phi = ash2(hb.y);
        #pragma unroll
        for (int j = 0; j < 6; ++j) {
            uint2 w = Wq2[(c0i + j) * 512 + i4];
            acc[j] = __builtin_amdgcn_fdot2(plo, ash2(w.x), acc[j], false);
            acc[j] = __builtin_amdgcn_fdot2(phi, ash2(w.y), acc[j], false);
        }
    }
    #pragma unroll
    for (int j = 0; j < 6; ++j) {
        float v = wave_sum(acc[j]);
        if (lane == 15) pred[c0i + j] = v;
    }
    __syncthreads();                       // bar3: pred ready

    // ---- Combine (per-wave redundant; readlane broadcast) ----
    float cv = 0.f;
    if (lane < 24) {
        int c = lane;
        float t = ftanh(pred[c]);
        if (c < 4)      cv = s_beta[c] * t + Bm[c];
        else if (c < 8) cv = s_alpha[(c - 4) * 4] * t + Am[c - 4];
        else            cv = s_alpha[c - 8] * t + Ar[c - 8];
    }
    float Bd[4], Amd[4], Ard[4][4];
    #pragma unroll
    for (int n = 0; n < 4; ++n) {
        Bd[n]  = rdlane(cv, n);
        Amd[n] = rdlane(cv, 4 + n);
    }
    #pragma unroll
    for (int i = 0; i < 4; ++i)
        #pragma unroll
        for (int j = 0; j < 4; ++j) Ard[i][j] = rdlane(cv, 8 + i * 4 + j);

    // ---- P3: outputs; thread owns float4 slots {tid, tid+256} ----
    #pragma unroll
    for (int t2 = 0; t2 < 2; ++t2) {
        int d4 = tid + 256 * t2;
        float4 h[4];
        #pragma unroll
        for (int n = 0; n < 4; ++n) {
            uint2 r = ((const uint2*)hq[n])[d4];
            h2 a = ash2(r.x), b = ash2(r.y);
            h[n].x = (float)a[0]; h[n].y = (float)a[1];
            h[n].z = (float)b[0]; h[n].w = (float)b[1];
        }
        float4 lv = t2 ? lv1 : lv0;
        float4 mx = {0.f, 0.f, 0.f, 0.f};
        #pragma unroll
        for (int n = 0; n < 4; ++n) {
            mx.x += Amd[n] * h[n].x; mx.y += Amd[n] * h[n].y;
            mx.z += Amd[n] * h[n].z; mx.w += Amd[n] * h[n].w;
        }
        #pragma unroll
        for (int i = 0; i < 4; ++i) {
            float4 o;
            o.x = Bd[i] * lv.x + mx.x;
            o.y = Bd[i] * lv.y + mx.y;
            o.z = Bd[i] * lv.z + mx.z;
            o.w = Bd[i] * lv.w + mx.w;
            #pragma unroll
            for (int j = 0; j < 4; ++j) {
                o.x += Ard[i][j] * h[j].x;
                o.y += Ard[i][j] * h[j].y;
                o.z += Ard[i][j] * h[j].z;
                o.w += Ard[i][j] * h[j].w;
            }
            out4[i * 512 + d4] = o;
        }
    }
}

extern "C" void kernel_launch(void* const* d_in, const int* in_sizes, int n_in,
                              void* d_out, int out_size, void* d_ws, size_t ws_size,
                              hipStream_t stream) {
    const float* lo      = (const float*)d_in[0];
    const float* hs      = (const float*)d_in[1];
    const float* Bm      = (const float*)d_in[2];
    const float* Am      = (const float*)d_in[3];
    const float* Ar      = (const float*)d_in[4];
    const float* s_alpha = (const float*)d_in[5];
    const float* s_beta  = (const float*)d_in[6];
    const float* Wb      = (const float*)d_in[7];
    const float* Wm      = (const float*)d_in[8];
    const float* Wr      = (const float*)d_in[9];
    float* out = (float*)d_out;

    unsigned int* Wq = (unsigned int*)d_ws;        // 98304 B

    wt_kernel<<<24, 256, 0, stream>>>(Wb, Wm, Wr, Wq);

    const int tokens = in_sizes[0] / D;            // 8192
    hc_kernel<<<tokens, BLK, 0, stream>>>(lo, hs, Bm, Am, Ar, s_alpha, s_beta,
                                          Wq, out);
}

// Round 18
// 131.036 us; speedup vs baseline: 2.0144x; 2.0144x over previous
//
#include <hip/hip_runtime.h>
#include <hip/hip_fp16.h>

#define D     2048
#define BLK   256
#define EPSV  1e-5f

typedef _Float16 h2 __attribute__((ext_vector_type(2)));

__device__ __forceinline__ unsigned int pkh(float a, float b) {
    return __builtin_bit_cast(unsigned int, __builtin_amdgcn_cvt_pkrtz(a, b));
}
__device__ __forceinline__ h2 ash2(unsigned int u) {
    return __builtin_bit_cast(h2, u);
}

// DPP row_shr:N add (old=0)
template<int CTRL>
__device__ __forceinline__ float dppadd(float x) {
    int y = __builtin_amdgcn_update_dpp(0, __builtin_bit_cast(int, x), CTRL, 0xf, 0xf, false);
    return x + __builtin_bit_cast(float, y);
}
// full wave64 sum; result valid in lanes 15,31,47,63
__device__ __forceinline__ float wave_sum(float x) {
    x += __shfl_xor(x, 32, 64);
    x += __shfl_xor(x, 16, 64);
    x = dppadd<0x111>(x);
    x = dppadd<0x112>(x);
    x = dppadd<0x114>(x);
    x = dppadd<0x118>(x);
    return x;
}

__device__ __forceinline__ float rdlane(float v, int l) {
    return __builtin_bit_cast(float, __builtin_amdgcn_readlane(__builtin_bit_cast(int, v), l));
}

// fast tanh via v_exp
__device__ __forceinline__ float ftanh(float x) {
    float xc = fminf(fmaxf(x, -10.f), 10.f);
    float e  = __expf(2.f * xc);
    return 1.f - 2.f * __builtin_amdgcn_rcpf(e + 1.f);
}

// ---- weight prep: Wq[c][p] = packed f16 pair of column c at d={2p,2p+1}
// c: 0-3 Wb, 4-7 Wm, 8-23 Wr(i*4+j). Grid: 24 blocks x 256 threads.
__global__ __launch_bounds__(256) void wt_kernel(
    const float* __restrict__ Wb, const float* __restrict__ Wm,
    const float* __restrict__ Wr, unsigned int* __restrict__ Wq)
{
    const int c = blockIdx.x;
    const int t = threadIdx.x;
    const float* src;
    int stride;
    if (c < 4)       { src = Wb + c;       stride = 4;  }
    else if (c < 8)  { src = Wm + (c - 4); stride = 4;  }
    else             { src = Wr + (c - 8); stride = 16; }

    #pragma unroll
    for (int k = 0; k < 4; ++k) {
        int p = t + 256 * k;                    // pair index 0..1023
        float a = src[(2 * p)     * stride];
        float b = src[(2 * p + 1) * stride];
        Wq[c * 1024 + p] = pkh(a, b);
    }
}

__global__ __launch_bounds__(BLK) void hc_kernel(
    const float* __restrict__ lo,      // [tok, D]
    const float* __restrict__ hs,      // [tok, 4, D]
    const float* __restrict__ Bm,      // [1,4]
    const float* __restrict__ Am,      // [4,1]
    const float* __restrict__ Ar,      // [4,4]
    const float* __restrict__ s_alpha, // [4,4]
    const float* __restrict__ s_beta,  // [1,4]
    const unsigned int* __restrict__ Wq, // [24][1024] packed f16 weight pairs
    float* __restrict__ out)           // [tok, 4, D]
{
    __shared__ __align__(16) unsigned int hq[4][1024];   // 16 KB packed f16 hidden rows
    __shared__ __align__(16) unsigned int hbar[1024];    //  4 KB packed f16 H_bar
    __shared__ float pred[24];
    __shared__ float sred[4][2];

    const int tid  = threadIdx.x;
    const int wave = tid >> 6;             // wave owns hidden row `wave`
    const int lane = tid & 63;
    const long tok = blockIdx.x;

    const float4* hs4  = (const float4*)(hs + tok * (long)(4 * D));
    const float4* lo4  = (const float4*)(lo + tok * (long)D);
    float4*       out4 = (float4*)(out + tok * (long)(4 * D));

    // ---- P1: wave streams its full row (unroll 4 caps in-flight regs), stats + f16 pack ----
    float s = 0.f, q = 0.f;
    uint2* hqw = (uint2*)hq[wave];
    #pragma unroll 4
    for (int k = 0; k < 8; ++k) {
        int i4 = 64 * k + lane;
        float4 v = hs4[wave * 512 + i4];
        s += v.x + v.y + v.z + v.w;
        q += v.x * v.x + v.y * v.y + v.z * v.z + v.w * v.w;
        hqw[i4] = make_uint2(pkh(v.x, v.y), pkh(v.z, v.w));
    }
    float4 lv0 = lo4[tid];                 // prefetch lo for P3
    float4 lv1 = lo4[tid + 256];
    s = wave_sum(s);
    q = wave_sum(q);
    if (lane == 15) { sred[wave][0] = s; sred[wave][1] = q; }
    __syncthreads();                       // bar1: hq + sred ready

    // ---- P1.5: build packed-f16 H_bar; thread owns uint2 slots {tid, tid+256} ----
    {
        float c1[4];                       // 0.25*rs[n]
        float c0 = 0.f;                    // -0.25*sum(mu*rs)
        #pragma unroll
        for (int n = 0; n < 4; ++n) {
            float ss = sred[n][0];
            float qq = sred[n][1];
            float m   = ss * (1.f / D);
            float var = qq * (1.f / D) - m * m;
            float r   = rsqrtf(var + EPSV);
            c1[n] = 0.25f * r;
            c0   -= 0.25f * r * m;
        }
        #pragma unroll
        for (int t2 = 0; t2 < 2; ++t2) {
            int slot = tid + 256 * t2;
            float b0 = c0, b1 = c0, b2 = c0, b3 = c0;
            #pragma unroll
            for (int n = 0; n < 4; ++n) {
                uint2 rw = ((const uint2*)hq[n])[slot];
                h2 a = ash2(rw.x), b = ash2(rw.y);
                b0 += (float)a[0] * c1[n];
                b1 += (float)a[1] * c1[n];
                b2 += (float)b[0] * c1[n];
                b3 += (float)b[1] * c1[n];
            }
            ((uint2*)hbar)[slot] = make_uint2(pkh(b0, b1), pkh(b2, b3));
        }
    }
    __syncthreads();                       // bar2: hbar ready

    // ---- P2: wave w dots cols 6w..6w+5 against full H_bar ----
    float acc[6] = {0.f, 0.f, 0.f, 0.f, 0.f, 0.f};
    const int c0i = wave * 6;
    const uint2* Wq2 = (const uint2*)Wq;   // [24][512]
    const uint2* hb2 = (const uint2*)hbar; // [512]

    #pragma unroll
    for (int k = 0; k < 8; ++k) {
        int i4 = 64 * k + lane;
        uint2 hb = hb2[i4];
        h2 plo = ash2(hb.x), phi = ash2(hb.y);
        #pragma unroll
        for (int j = 0; j < 6; ++j) {
            uint2 w = Wq2[(c0i + j) * 512 + i4];
            acc[j] = __builtin_amdgcn_fdot2(plo, ash2(w.x), acc[j], false);
            acc[j] = __builtin_amdgcn_fdot2(phi, ash2(w.y), acc[j], false);
        }
    }
    #pragma unroll
    for (int j = 0; j < 6; ++j) {
        float v = wave_sum(acc[j]);
        if (lane == 15) pred[c0i + j] = v;
    }
    __syncthreads();                       // bar3: pred ready

    // ---- Combine (per-wave redundant; readlane broadcast) ----
    float cv = 0.f;
    if (lane < 24) {
        int c = lane;
        float t = ftanh(pred[c]);
        if (c < 4)      cv = s_beta[c] * t + Bm[c];
        else if (c < 8) cv = s_alpha[(c - 4) * 4] * t + Am[c - 4];
        else            cv = s_alpha[c - 8] * t + Ar[c - 8];
    }
    float Bd[4], Amd[4], Ard[4][4];
    #pragma unroll
    for (int n = 0; n < 4; ++n) {
        Bd[n]  = rdlane(cv, n);
        Amd[n] = rdlane(cv, 4 + n);
    }
    #pragma unroll
    for (int i = 0; i < 4; ++i)
        #pragma unroll
        for (int j = 0; j < 4; ++j) Ard[i][j] = rdlane(cv, 8 + i * 4 + j);

    // ---- P3: outputs; thread owns float4 slots {tid, tid+256} ----
    #pragma unroll
    for (int t2 = 0; t2 < 2; ++t2) {
        int d4 = tid + 256 * t2;
        float4 h[4];
        #pragma unroll
        for (int n = 0; n < 4; ++n) {
            uint2 r = ((const uint2*)hq[n])[d4];
            h2 a = ash2(r.x), b = ash2(r.y);
            h[n].x = (float)a[0]; h[n].y = (float)a[1];
            h[n].z = (float)b[0]; h[n].w = (float)b[1];
        }
        float4 lv = t2 ? lv1 : lv0;
        float4 mx = {0.f, 0.f, 0.f, 0.f};
        #pragma unroll
        for (int n = 0; n < 4; ++n) {
            mx.x += Amd[n] * h[n].x; mx.y += Amd[n] * h[n].y;
            mx.z += Amd[n] * h[n].z; mx.w += Amd[n] * h[n].w;
        }
        #pragma unroll
        for (int i = 0; i < 4; ++i) {
            float4 o;
            o.x = Bd[i] * lv.x + mx.x;
            o.y = Bd[i] * lv.y + mx.y;
            o.z = Bd[i] * lv.z + mx.z;
            o.w = Bd[i] * lv.w + mx.w;
            #pragma unroll
            for (int j = 0; j < 4; ++j) {
                o.x += Ard[i][j] * h[j].x;
                o.y += Ard[i][j] * h[j].y;
                o.z += Ard[i][j] * h[j].z;
                o.w += Ard[i][j] * h[j].w;
            }
            out4[i * 512 + d4] = o;
        }
    }
}

extern "C" void kernel_launch(void* const* d_in, const int* in_sizes, int n_in,
                              void* d_out, int out_size, void* d_ws, size_t ws_size,
                              hipStream_t stream) {
    const float* lo      = (const float*)d_in[0];
    const float* hs      = (const float*)d_in[1];
    const float* Bm      = (const float*)d_in[2];
    const float* Am      = (const float*)d_in[3];
    const float* Ar      = (const float*)d_in[4];
    const float* s_alpha = (const float*)d_in[5];
    const float* s_beta  = (const float*)d_in[6];
    const float* Wb      = (const float*)d_in[7];
    const float* Wm      = (const float*)d_in[8];
    const float* Wr      = (const float*)d_in[9];
    float* out = (float*)d_out;

    unsigned int* Wq = (unsigned int*)d_ws;        // 98304 B

    wt_kernel<<<24, 256, 0, stream>>>(Wb, Wm, Wr, Wq);

    const int tokens = in_sizes[0] / D;            // 8192
    hc_kernel<<<tokens, BLK, 0, stream>>>(lo, hs, Bm, Am, Ar, s_alpha, s_beta,
                                          Wq, out);
}